// Round 8
// baseline (121.552 us; speedup 1.0000x reference)
//
#include <hip/hip_runtime.h>
#include <math.h>

typedef float f32x4 __attribute__((ext_vector_type(4)));

// Problem constants: bs=8, n=32, dy=64, dc=256, M=8, nm=256.
// out[b, i*8+a, j*8+c, ch] = (W[ch,:]·E[b,i,j,:] + Cpe[a*8+c, ch])
//                            * m1[b,i] * m2[b, (j%4)*8+c]
// Prologue builds Cpe = W·pe (64x256) and Wt = W^T (64x256) in d_ws.

// ---------- Prologue: Cpe[pos][ch] and Wt[d][ch] ----------
__global__ __launch_bounds__(256) void prep_kernel(const float* __restrict__ W,
                                                   float* __restrict__ Cpe,
                                                   float* __restrict__ Wt) {
    const int pos = blockIdx.x;      // 0..63 (= pe position, and = d for Wt)
    const int t   = threadIdx.x;     // channel
    Wt[pos * 256 + t] = W[t * 64 + pos];   // transpose: Wt[d][ch]
    __shared__ float peL[64];
    if (t < 64) {
        const float k2  = (float)(t & ~1);
        const float div = expf(-k2 * (logf(10000.0f) / 64.0f));
        const float arg = (float)pos * div;
        peL[t] = (t & 1) ? cosf(arg) : sinf(arg);
    }
    __syncthreads();
    const f32x4* W4 = (const f32x4*)W;
    float acc = 0.0f;
#pragma unroll
    for (int d4 = 0; d4 < 16; ++d4) {
        f32x4 w = W4[t * 16 + d4];
        acc += w.x * peL[4 * d4 + 0] + w.y * peL[4 * d4 + 1] +
               w.z * peL[4 * d4 + 2] + w.w * peL[4 * d4 + 3];
    }
    Cpe[pos * 256 + t] = acc;
}

// ---------- Main: block = one (b,ii) output row (256 KB contiguous).
// Wave w owns jj in [w*64, w*64+64) -> j = w*8..w*8+7; lane g owns channel
// quad 4g..4g+3. a = ii&7 fixed per block -> only 8 Cpe quads, loaded once.
// Store loop = 64 purely sequential 1 KB wave-stores (64 KB/wave).
// XCD swizzle: each XCD gets 256 consecutive blocks = contiguous 64 MB.
__global__ __launch_bounds__(256) void etoc_stream(const float* __restrict__ E,
                                                   const float* __restrict__ m1p,
                                                   const float* __restrict__ m2p,
                                                   const float* __restrict__ Wt,
                                                   const float* __restrict__ Cpe,
                                                   float* __restrict__ out) {
    const int bid = blockIdx.x;              // 0..2047
    const int blk = (bid & 7) * 256 + (bid >> 3);   // bijective XCD swizzle
    const int ii = blk & 255;
    const int b  = blk >> 8;
    const int i = ii >> 3, a = ii & 7;
    const int t = threadIdx.x;
    const int w = t >> 6;                    // wave id: jj quarter
    const int g = t & 63;                    // channel quad

    // ---- dot: acc[jl][4g..4g+3] = sum_d Wt[d][4g..4g+3] * E[b,i,w*8+jl,d]
    const f32x4* Wt4 = (const f32x4*)Wt;
    const f32x4* E4  = (const f32x4*)E;
    const int ebase = ((b * 32 + i) * 32 + w * 8) * 16;   // f4 units
    f32x4 acc[8];
#pragma unroll
    for (int jl = 0; jl < 8; ++jl) acc[jl] = (f32x4){0, 0, 0, 0};
#pragma unroll 4
    for (int d4 = 0; d4 < 16; ++d4) {
        f32x4 e[8];
#pragma unroll
        for (int jl = 0; jl < 8; ++jl) e[jl] = E4[ebase + jl * 16 + d4];  // uniform
#pragma unroll
        for (int dd = 0; dd < 4; ++dd) {
            const f32x4 wv = Wt4[(d4 * 4 + dd) * 64 + g];   // lane-coalesced
#pragma unroll
            for (int jl = 0; jl < 8; ++jl) acc[jl] += wv * e[jl][dd];
        }
    }

    // ---- masks: mm[k][l] = m1 * m2[b][4k+l]  (mask index = jj%32)
    const float m1v = m1p[b * 32 + i];
    f32x4 mm[8];
    const f32x4* m2v = (const f32x4*)(m2p + b * 32);
#pragma unroll
    for (int k = 0; k < 8; ++k) mm[k] = m2v[k] * m1v;

    // ---- Cpe quads for fixed a: q[c], c = jj&7
    const f32x4* Cpe4 = (const f32x4*)Cpe;
    f32x4 q[8];
#pragma unroll
    for (int c = 0; c < 8; ++c) q[c] = Cpe4[(a * 8 + c) * 64 + g];

    // ---- stores: 64 sequential rows (jj = w*64 + r), 1 KB per wave-store
    f32x4* out4 = (f32x4*)out;
    const size_t base = ((size_t)blk * 256 + (size_t)w * 64) * 64 + (size_t)g;
#pragma unroll
    for (int r = 0; r < 64; ++r) {
        const int jl = r >> 3;
        const int c  = r & 7;
        const int mr = r & 31;
        const f32x4 v = (acc[jl] + q[c]) * mm[mr >> 2][mr & 3];
        __builtin_nontemporal_store(v, &out4[base + (size_t)r * 64]);
    }
}

extern "C" void kernel_launch(void* const* d_in, const int* in_sizes, int n_in,
                              void* d_out, int out_size, void* d_ws, size_t ws_size,
                              hipStream_t stream) {
    const float* E   = (const float*)d_in[0];   // (8,32,32,64)
    const float* m1p = (const float*)d_in[1];   // (8,32,1,1)
    const float* m2p = (const float*)d_in[2];   // (8,1,32,1)
    const float* W   = (const float*)d_in[3];   // (256,64)
    float* out = (float*)d_out;                 // (8,256,256,256)

    float* Cpe = (float*)d_ws;                  // 64 KB
    float* Wt  = (float*)((char*)d_ws + 65536); // 64 KB

    prep_kernel<<<64, 256, 0, stream>>>(W, Cpe, Wt);
    etoc_stream<<<2048, 256, 0, stream>>>(E, m1p, m2p, Wt, Cpe, out);
}

// Round 9
// 107.699 us; speedup vs baseline: 1.1286x; 1.1286x over previous
//
#include <hip/hip_runtime.h>
#include <math.h>

typedef float f32x4 __attribute__((ext_vector_type(4)));

// Problem constants: bs=8, n=32, dy=64, dc=256, M=8, nm=256.
// out[b, i*8+a, j*8+c, ch] = (W[ch,:]·E[b,i,j,:] + Cpe[a*8+c, ch]) * m1[b,i] * m2[b, (j%4)*8+c]
// Prologue builds Cpe = W·pe (64x256) and Wt = W^T (64x256) in d_ws.
// ROUND 9 = exact restore of round-5 best (107.8 us). Falsified since:
// NT-vs-plain (null), 4 blocks/CU (null), Cpe pipelining (null),
// row-contiguous stores + XCD swizzle (regression).

// ---------- Prologue: Cpe[pos][ch] and Wt[d][ch] ----------
__global__ __launch_bounds__(256) void prep_kernel(const float* __restrict__ W,
                                                   float* __restrict__ Cpe,
                                                   float* __restrict__ Wt) {
    const int pos = blockIdx.x;      // 0..63 (= pe position, and = d for Wt)
    const int t   = threadIdx.x;     // channel
    Wt[pos * 256 + t] = W[t * 64 + pos];   // transpose: Wt[d][ch]
    __shared__ float peL[64];
    if (t < 64) {
        const float k2  = (float)(t & ~1);
        const float div = expf(-k2 * (logf(10000.0f) / 64.0f));
        const float arg = (float)pos * div;
        peL[t] = (t & 1) ? cosf(arg) : sinf(arg);
    }
    __syncthreads();
    const f32x4* W4 = (const f32x4*)W;
    float acc = 0.0f;
#pragma unroll
    for (int d4 = 0; d4 < 16; ++d4) {
        f32x4 w = W4[t * 16 + d4];
        acc += w.x * peL[4 * d4 + 0] + w.y * peL[4 * d4 + 1] +
               w.z * peL[4 * d4 + 2] + w.w * peL[4 * d4 + 3];
    }
    Cpe[pos * 256 + t] = acc;
}

// ---------- Main: no LDS, no barriers. Block = (b, i, h); wave w owns
// j = h*16 + w*4 .. +4; lane g owns channel quad 4g..4g+3.
// Each thread computes its own ce quads (coalesced Wt loads, broadcast E
// loads), then streams 8a x 4j x 8c = 256 nontemporal 16B stores.
__global__ __launch_bounds__(256) void etoc_stream(const float* __restrict__ E,
                                                   const float* __restrict__ m1p,
                                                   const float* __restrict__ m2p,
                                                   const float* __restrict__ Wt,
                                                   const float* __restrict__ Cpe,
                                                   float* __restrict__ out) {
    const int blk = blockIdx.x;      // b*64 + i*2 + h
    const int h = blk & 1;
    const int i = (blk >> 1) & 31;
    const int b = blk >> 6;
    const int t = threadIdx.x;
    const int w = t >> 6;            // wave id
    const int g = t & 63;            // channel quad
    const int j0 = h * 16 + w * 4;   // first j of this wave

    // ce[jl][4g..4g+3] = sum_d Wt[d][4g..4g+3] * E[b,i,j0+jl,d]
    const f32x4* Wt4 = (const f32x4*)Wt;
    const f32x4* E4  = (const f32x4*)E;
    const int ebase = ((b * 32 + i) * 32 + j0) * 16;   // f4 units
    f32x4 acc0 = {0,0,0,0}, acc1 = {0,0,0,0}, acc2 = {0,0,0,0}, acc3 = {0,0,0,0};
#pragma unroll 4
    for (int d4 = 0; d4 < 16; ++d4) {
        const f32x4 e0 = E4[ebase + 0 * 16 + d4];   // wave-uniform broadcast
        const f32x4 e1 = E4[ebase + 1 * 16 + d4];
        const f32x4 e2 = E4[ebase + 2 * 16 + d4];
        const f32x4 e3 = E4[ebase + 3 * 16 + d4];
#pragma unroll
        for (int dd = 0; dd < 4; ++dd) {
            const f32x4 wv = Wt4[(d4 * 4 + dd) * 64 + g];   // lane-coalesced
            acc0 += wv * e0[dd];
            acc1 += wv * e1[dd];
            acc2 += wv * e2[dd];
            acc3 += wv * e3[dd];
        }
    }

    // combined masks: mm[2*jl + (c>>2)][c&3] = m1 * m2[jl*8+c]
    const float m1v = m1p[b * 32 + i];
    f32x4 mm[8];
    const f32x4* m2v = (const f32x4*)(m2p + b * 32);
#pragma unroll
    for (int k = 0; k < 8; ++k) mm[k] = m2v[k] * m1v;

    const f32x4* Cpe4 = (const f32x4*)Cpe;
    f32x4* out4 = (f32x4*)out;
    // out row = (b*256 + i*8 + a)*256 + (j0+jl)*8 + c ; f4 idx = row*64 + g
    const size_t rowb = ((size_t)(b * 256 + i * 8) * 256 + (size_t)j0 * 8);

#pragma unroll 1
    for (int a = 0; a < 8; ++a) {
        f32x4 q[8];
#pragma unroll
        for (int c = 0; c < 8; ++c) q[c] = Cpe4[(a * 8 + c) * 64 + g];
#pragma unroll
        for (int jl = 0; jl < 4; ++jl) {
            const f32x4 ce = (jl == 0) ? acc0 : (jl == 1) ? acc1 : (jl == 2) ? acc2 : acc3;
            const size_t base = (rowb + (size_t)a * 256 + (size_t)jl * 8) * 64 + (size_t)g;
#pragma unroll
            for (int c = 0; c < 8; ++c) {
                const float m = mm[2 * jl + (c >> 2)][c & 3];
                f32x4 r = (ce + q[c]) * m;
                __builtin_nontemporal_store(r, &out4[base + (size_t)c * 64]);
            }
        }
    }
}

extern "C" void kernel_launch(void* const* d_in, const int* in_sizes, int n_in,
                              void* d_out, int out_size, void* d_ws, size_t ws_size,
                              hipStream_t stream) {
    const float* E   = (const float*)d_in[0];   // (8,32,32,64)
    const float* m1p = (const float*)d_in[1];   // (8,32,1,1)
    const float* m2p = (const float*)d_in[2];   // (8,1,32,1)
    const float* W   = (const float*)d_in[3];   // (256,64)
    float* out = (float*)d_out;                 // (8,256,256,256)

    float* Cpe = (float*)d_ws;                  // 64 KB
    float* Wt  = (float*)((char*)d_ws + 65536); // 64 KB

    prep_kernel<<<64, 256, 0, stream>>>(W, Cpe, Wt);
    etoc_stream<<<512, 256, 0, stream>>>(E, m1p, m2p, Wt, Cpe, out);
}